// Round 3
// baseline (108.072 us; speedup 1.0000x reference)
//
#include <hip/hip_runtime.h>

#define T 32
#define BLOCK 256
#define GRID 2048

// Round-1 structure (direct per-thread row loads — L1 serves 7/8 of the
// float4s per line) with the final reduction fused in via deterministic
// fixed-point integer atomics + last-block-writes-out.
__global__ __launch_bounds__(BLOCK) void mel_fused(const float* __restrict__ probs,
                                                   int nrows, int nlaunched,
                                                   unsigned long long* __restrict__ ws,
                                                   float* __restrict__ out) {
    const int tid = blockIdx.x * blockDim.x + threadIdx.x;
    const int stride = gridDim.x * blockDim.x;

    double acc = 0.0;
    for (int row = tid; row < nrows; row += stride) {
        const float4* rp = reinterpret_cast<const float4*>(probs + (size_t)row * T);
        float p[T];
        #pragma unroll
        for (int k = 0; k < T / 4; ++k) {
            float4 v = rp[k];
            p[4 * k + 0] = v.x;
            p[4 * k + 1] = v.y;
            p[4 * k + 2] = v.z;
            p[4 * k + 3] = v.w;
        }

        // suffix products of (1 - p): suf[i] = prod_{j>i} (1 - p_j)
        float suf[T];
        suf[T - 1] = 1.0f;
        #pragma unroll
        for (int i = T - 2; i >= 0; --i) suf[i] = suf[i + 1] * (1.0f - p[i + 1]);

        // forward: q_i = pre_i * suf_i ; s = (s + p_i) * q_i ; pre *= (1 - p_i)
        float pre = 1.0f;
        float s = 0.0f;
        #pragma unroll
        for (int i = 0; i < T; ++i) {
            float q = pre * suf[i];
            s = (s + p[i]) * q;
            pre *= (1.0f - p[i]);
        }
        acc += (double)s;
    }

    // ---- deterministic block reduction ----
    #pragma unroll
    for (int off = 32; off > 0; off >>= 1)
        acc += __shfl_down(acc, off, 64);

    __shared__ double sred[BLOCK / 64];
    const int lane = threadIdx.x & 63;
    const int wid = threadIdx.x >> 6;
    if (lane == 0) sred[wid] = acc;
    __syncthreads();
    if (threadIdx.x == 0) {
        double b = sred[0] + sred[1] + sred[2] + sred[3];
        // fixed-point 2^36: integer atomics commute exactly -> deterministic.
        // |sum| < 2^21, scaled < 2^57 fits; quantization error on loss < 1e-14.
        long long fx = __double2ll_rn(b * 68719476736.0);
        atomicAdd(ws, (unsigned long long)fx);
        __threadfence();
        unsigned int old = atomicAdd((unsigned int*)(ws + 1), 1u);
        if (old == (unsigned int)(nlaunched - 1)) {
            __threadfence();
            unsigned long long tot = atomicAdd(ws, 0ULL);
            double total = (double)(long long)tot * (1.0 / 68719476736.0);
            out[0] = (float)(-total / (double)nrows);
        }
    }
}

extern "C" void kernel_launch(void* const* d_in, const int* in_sizes, int n_in,
                              void* d_out, int out_size, void* d_ws, size_t ws_size,
                              hipStream_t stream) {
    const float* probs = (const float*)d_in[0];
    float* out = (float*)d_out;
    const int nrows = in_sizes[0] / T;

    hipMemsetAsync(d_ws, 0, 16, stream);   // zero fixed-point acc + arrival counter
    mel_fused<<<GRID, BLOCK, 0, stream>>>(probs, nrows, GRID,
                                          (unsigned long long*)d_ws, out);
}

// Round 4
// 46.323 us; speedup vs baseline: 2.3330x; 2.3330x over previous
//
#include <hip/hip_runtime.h>

#define T 32
#define BLOCK 256
#define GRID 4096

// Kernel 1: per-row loss term + deterministic per-block partial sums (double).
// Plain stores to distinct addresses — no atomics, no fences (round-3 lesson:
// contended same-line device atomics + threadfence cost ~60 us).
__global__ __launch_bounds__(BLOCK) void mel_rows(const float* __restrict__ probs,
                                                  double* __restrict__ partials,
                                                  int nrows) {
    const int tid = blockIdx.x * blockDim.x + threadIdx.x;
    const int stride = gridDim.x * blockDim.x;

    double acc = 0.0;
    for (int row = tid; row < nrows; row += stride) {
        const float4* rp = reinterpret_cast<const float4*>(probs + (size_t)row * T);
        float p[T];
        #pragma unroll
        for (int k = 0; k < T / 4; ++k) {
            float4 v = rp[k];
            p[4 * k + 0] = v.x;
            p[4 * k + 1] = v.y;
            p[4 * k + 2] = v.z;
            p[4 * k + 3] = v.w;
        }

        // suffix products of (1 - p): suf[i] = prod_{j>i} (1 - p_j)
        float suf[T];
        suf[T - 1] = 1.0f;
        #pragma unroll
        for (int i = T - 2; i >= 0; --i) suf[i] = suf[i + 1] * (1.0f - p[i + 1]);

        // forward: q_i = pre_i * suf_i ; s = (s + p_i) * q_i ; pre *= (1 - p_i)
        float pre = 1.0f;
        float s = 0.0f;
        #pragma unroll
        for (int i = 0; i < T; ++i) {
            float q = pre * suf[i];
            s = (s + p[i]) * q;
            pre *= (1.0f - p[i]);
        }
        acc += (double)s;
    }

    // wave (64-lane) reduction
    #pragma unroll
    for (int off = 32; off > 0; off >>= 1)
        acc += __shfl_down(acc, off, 64);

    __shared__ double sdata[BLOCK / 64];
    const int lane = threadIdx.x & 63;
    const int wid = threadIdx.x >> 6;
    if (lane == 0) sdata[wid] = acc;
    __syncthreads();
    if (threadIdx.x == 0) {
        double b = sdata[0] + sdata[1] + sdata[2] + sdata[3];
        partials[blockIdx.x] = b;
    }
}

// Kernel 2: deterministic reduction of GRID partials -> scalar loss.
__global__ __launch_bounds__(BLOCK) void mel_final(const double* __restrict__ partials,
                                                   float* __restrict__ out,
                                                   int nrows) {
    double acc = 0.0;
    for (int i = threadIdx.x; i < GRID; i += BLOCK) acc += partials[i];

    #pragma unroll
    for (int off = 32; off > 0; off >>= 1)
        acc += __shfl_down(acc, off, 64);

    __shared__ double sdata[BLOCK / 64];
    const int lane = threadIdx.x & 63;
    const int wid = threadIdx.x >> 6;
    if (lane == 0) sdata[wid] = acc;
    __syncthreads();
    if (threadIdx.x == 0) {
        double b = sdata[0] + sdata[1] + sdata[2] + sdata[3];
        out[0] = (float)(-b / (double)nrows);
    }
}

extern "C" void kernel_launch(void* const* d_in, const int* in_sizes, int n_in,
                              void* d_out, int out_size, void* d_ws, size_t ws_size,
                              hipStream_t stream) {
    const float* probs = (const float*)d_in[0];
    float* out = (float*)d_out;
    double* partials = (double*)d_ws;  // GRID doubles = 32 KB
    const int nrows = in_sizes[0] / T;

    mel_rows<<<GRID, BLOCK, 0, stream>>>(probs, partials, nrows);
    mel_final<<<1, BLOCK, 0, stream>>>(partials, out, nrows);
}

// Round 5
// 44.810 us; speedup vs baseline: 2.4118x; 1.0338x over previous
//
#include <hip/hip_runtime.h>

#define T 32
#define BLOCK 256
#define GRID 2048

// Best-known config (round 1, 45.0 us): one pass, one thread per row,
// float4 row loads (L1 serves the within-line re-reads), per-row f32 scan
// identical to the reference order, double partials via plain stores,
// tiny second kernel for the deterministic final sum.
__global__ __launch_bounds__(BLOCK) void mel_rows(const float* __restrict__ probs,
                                                  double* __restrict__ partials,
                                                  int nrows) {
    const int tid = blockIdx.x * blockDim.x + threadIdx.x;
    const int stride = gridDim.x * blockDim.x;

    double acc = 0.0;
    for (int row = tid; row < nrows; row += stride) {
        const float4* rp = reinterpret_cast<const float4*>(probs + (size_t)row * T);
        float p[T];
        #pragma unroll
        for (int k = 0; k < T / 4; ++k) {
            float4 v = rp[k];
            p[4 * k + 0] = v.x;
            p[4 * k + 1] = v.y;
            p[4 * k + 2] = v.z;
            p[4 * k + 3] = v.w;
        }

        // suffix products of (1 - p): suf[i] = prod_{j>i} (1 - p_j)
        float suf[T];
        suf[T - 1] = 1.0f;
        #pragma unroll
        for (int i = T - 2; i >= 0; --i) suf[i] = suf[i + 1] * (1.0f - p[i + 1]);

        // forward: q_i = pre_i * suf_i ; s = (s + p_i) * q_i ; pre *= (1 - p_i)
        float pre = 1.0f;
        float s = 0.0f;
        #pragma unroll
        for (int i = 0; i < T; ++i) {
            float q = pre * suf[i];
            s = (s + p[i]) * q;
            pre *= (1.0f - p[i]);
        }
        acc += (double)s;
    }

    // wave (64-lane) reduction
    #pragma unroll
    for (int off = 32; off > 0; off >>= 1)
        acc += __shfl_down(acc, off, 64);

    __shared__ double sdata[BLOCK / 64];
    const int lane = threadIdx.x & 63;
    const int wid = threadIdx.x >> 6;
    if (lane == 0) sdata[wid] = acc;
    __syncthreads();
    if (threadIdx.x == 0) {
        double b = sdata[0] + sdata[1] + sdata[2] + sdata[3];
        partials[blockIdx.x] = b;
    }
}

// Kernel 2: deterministic reduction of GRID partials -> scalar loss.
__global__ __launch_bounds__(BLOCK) void mel_final(const double* __restrict__ partials,
                                                   float* __restrict__ out,
                                                   int nrows) {
    double acc = 0.0;
    for (int i = threadIdx.x; i < GRID; i += BLOCK) acc += partials[i];

    #pragma unroll
    for (int off = 32; off > 0; off >>= 1)
        acc += __shfl_down(acc, off, 64);

    __shared__ double sdata[BLOCK / 64];
    const int lane = threadIdx.x & 63;
    const int wid = threadIdx.x >> 6;
    if (lane == 0) sdata[wid] = acc;
    __syncthreads();
    if (threadIdx.x == 0) {
        double b = sdata[0] + sdata[1] + sdata[2] + sdata[3];
        out[0] = (float)(-b / (double)nrows);
    }
}

extern "C" void kernel_launch(void* const* d_in, const int* in_sizes, int n_in,
                              void* d_out, int out_size, void* d_ws, size_t ws_size,
                              hipStream_t stream) {
    const float* probs = (const float*)d_in[0];
    float* out = (float*)d_out;
    double* partials = (double*)d_ws;  // GRID doubles = 16 KB
    const int nrows = in_sizes[0] / T;

    mel_rows<<<GRID, BLOCK, 0, stream>>>(probs, partials, nrows);
    mel_final<<<1, BLOCK, 0, stream>>>(partials, out, nrows);
}